// Round 3
// baseline (252.121 us; speedup 1.0000x reference)
//
#include <hip/hip_runtime.h>
#include <stdint.h>

// Fused 2-layer LSTM (B=32768, T=64, F=8, H=16) + FC(16->512,relu) + FC(512->32)
// One wave = 16 batch elements. bf16 hi/lo split MFMA (16x16x32), fp32 accum.
// This round: LSTM1(t) software-pipelined with LSTM2(t-1) (one LDS fence/step),
// A-fragments staged in LDS in final layout (single b128 reads, no cndmask
// builds), x prefetched one step ahead, biases hoisted, FC weight prefetch.

#define NT 64
#define NF 8

typedef __attribute__((ext_vector_type(8))) short bf16x8;
typedef __attribute__((ext_vector_type(4))) float f32x4;

#define MFMA16 __builtin_amdgcn_mfma_f32_16x16x32_bf16

static __device__ __forceinline__ short f2bf(float f) {
  uint32_t u = __float_as_uint(f);
  u += 0x7FFFu + ((u >> 16) & 1u);          // RTNE to bf16
  return (short)(u >> 16);
}
static __device__ __forceinline__ float bf2f(short s) {
  return __uint_as_float(((uint32_t)(uint16_t)s) << 16);
}
static __device__ __forceinline__ void split_hl(float f, short& hi, short& lo) {
  short h = f2bf(f);
  hi = h;
  lo = f2bf(f - bf2f(h));                    // Dekker residual, exact then RTNE
}
static __device__ __forceinline__ float sigmoidf_(float v) {
  return __builtin_amdgcn_rcpf(1.0f + __expf(-v));
}
// write->read fence: waitcnt for LDS completion + compiler memory order.
// No sched_barrier: all DS ops are compiler-visible (deps tracked), and we
// WANT global loads / VALU to schedule across.
static __device__ __forceinline__ void lds_fence() {
  asm volatile("s_waitcnt lgkmcnt(0)" ::: "memory");
}
// compiler-only ordering (zero instructions): read phase before write phase
static __device__ __forceinline__ void cbar() {
  asm volatile("" ::: "memory");
}

__global__ __launch_bounds__(256, 2) void lstm_fused(
    const float* __restrict__ x,
    const float* __restrict__ W1, const float* __restrict__ U1, const float* __restrict__ b1,
    const float* __restrict__ W2, const float* __restrict__ U2, const float* __restrict__ b2,
    const float* __restrict__ Wfc1, const float* __restrict__ bfc1,
    const float* __restrict__ Wfc2, const float* __restrict__ bfc2,
    float* __restrict__ out)
{
  const int tid  = threadIdx.x;
  const int lane = tid & 63;
  const int wv   = tid >> 6;
  const int col  = lane & 15;   // batch row (A) / gate col (C)
  const int g    = lane >> 4;   // K-group (slots 8g..8g+7)
  const int base = (blockIdx.x * 4 + wv) * 16;

  // per-wave LDS (shorts):
  //  L1A_hi[16][32]: A1 for LSTM1 = [xh(8) | xl(8) | h1h(16)]
  //  L1A_lo[16][32]: A3 for LSTM1 = [0 | 0 | h1l(16)]
  //  L2A_hi[16][32]: A1 for LSTM2 = [h1h(16) | h2h(16)]
  //  L2A_lo[16][32]: A3 for LSTM2 = [h1l(16) | h2l(16)]
  //  cf_hi[16][40], cf_lo[16][40]: FC1->FC2 staging
  __shared__ __align__(16) short lds_all[4][4 * 512 + 2 * 640];
  short* const l1h = &lds_all[wv][0];
  short* const l1l = l1h + 512;
  short* const l2h = l1h + 1024;
  short* const l2l = l1h + 1536;
  short* const cfh = l1h + 2048;
  short* const cfl = l1h + 2048 + 640;

  // zero the 4KB A-staging region (h(-1)=0, h2(-1)=0, A3 x-slots stay 0)
  {
    int4 z4 = make_int4(0, 0, 0, 0);
    int4* p = (int4*)l1h;
#pragma unroll
    for (int i = 0; i < 4; ++i) p[lane + 64 * i] = z4;
  }
  cbar();

  // ---- static B-fragments (weights), hi/lo split ----
  // LSTM1: B1a = [W1h; W1h; U1h], B2a = [W1l; 0; U1l]
  // LSTM2: B1b = [W2h; U2h],      B2b = [W2l; U2l]
  bf16x8 B1a[4], B2a[4], B1b[4], B2b[4];
#pragma unroll
  for (int n = 0; n < 4; ++n) {
    const int c = 16 * n + col;
#pragma unroll
    for (int j = 0; j < 8; ++j) {
      const int k = 8 * g + j;
      short h, l;
      if (k < 8)       { split_hl(W1[k * 64 + c], h, l);        B1a[n][j] = h; B2a[n][j] = l; }
      else if (k < 16) { split_hl(W1[(k - 8) * 64 + c], h, l);  B1a[n][j] = h; B2a[n][j] = 0; }
      else             { split_hl(U1[(k - 16) * 64 + c], h, l); B1a[n][j] = h; B2a[n][j] = l; }
      short h2, l2;
      if (k < 16) split_hl(W2[k * 64 + c], h2, l2);
      else        split_hl(U2[(k - 16) * 64 + c], h2, l2);
      B1b[n][j] = h2; B2b[n][j] = l2;
    }
  }

  f32x4 bias1v[4], bias2v[4];
#pragma unroll
  for (int n = 0; n < 4; ++n) {
    float b1s = b1[16 * n + col];
    float b2s = b2[16 * n + col];
    bias1v[n] = (f32x4){b1s, b1s, b1s, b1s};
    bias2v[n] = (f32x4){b2s, b2s, b2s, b2s};
  }

  const short* const aL1h = l1h + col * 32 + 8 * g;
  const short* const aL1l = l1l + col * 32 + 8 * g;
  const short* const aL2h = l2h + col * 32 + 8 * g;
  const short* const aL2l = l2l + col * 32 + 8 * g;

  const float* xrow = x + (size_t)(base + col) * (NT * NF);

  // ---- prologue: stash x(0) ----
  {
    f32x4 xa = *(const f32x4*)(xrow);
    f32x4 xb = *(const f32x4*)(xrow + 4);
    bf16x8 xh8, xl8;
#pragma unroll
    for (int j = 0; j < 4; ++j) {
      short h, l;
      split_hl(xa[j], h, l); xh8[j] = h;     xl8[j] = l;
      split_hl(xb[j], h, l); xh8[4 + j] = h; xl8[4 + j] = l;
    }
    if (g == 0)      *(bf16x8*)(l1h + col * 32)     = xh8;
    else if (g == 1) *(bf16x8*)(l1h + col * 32 + 8) = xl8;
  }
  lds_fence();

  f32x4 c1 = {0.f, 0.f, 0.f, 0.f};
  f32x4 c2 = {0.f, 0.f, 0.f, 0.f};
  f32x4 h1v, h2v;

  // ---- iter 0: LSTM1(0) only ----
  {
    bf16x8 A1 = *(const bf16x8*)aL1h;
    bf16x8 A3 = *(const bf16x8*)aL1l;
    f32x4 xa = *(const f32x4*)(xrow + NF);      // x(1)
    f32x4 xb = *(const f32x4*)(xrow + NF + 4);
    f32x4 z[4];
#pragma unroll
    for (int n = 0; n < 4; ++n) {
      f32x4 zi = bias1v[n];
      zi = MFMA16(A1, B1a[n], zi, 0, 0, 0);
      zi = MFMA16(A1, B2a[n], zi, 0, 0, 0);
      zi = MFMA16(A3, B1a[n], zi, 0, 0, 0);
      z[n] = zi;
    }
#pragma unroll
    for (int r = 0; r < 4; ++r) {
      float ig = sigmoidf_(z[0][r]);
      float fg = sigmoidf_(z[1][r]);
      float gg = fmaxf(z[2][r], 0.f);
      float og = sigmoidf_(z[3][r]);
      float cc = fg * c1[r] + ig * gg;
      c1[r] = cc;
      h1v[r] = og * fmaxf(cc, 0.f);
    }
    cbar();
    // stash x(1)
    bf16x8 xh8, xl8;
#pragma unroll
    for (int j = 0; j < 4; ++j) {
      short h, l;
      split_hl(xa[j], h, l); xh8[j] = h;     xl8[j] = l;
      split_hl(xb[j], h, l); xh8[4 + j] = h; xl8[4 + j] = l;
    }
    if (g == 0)      *(bf16x8*)(l1h + col * 32)     = xh8;
    else if (g == 1) *(bf16x8*)(l1h + col * 32 + 8) = xl8;
    // write h1(0) into both consumers' layouts
#pragma unroll
    for (int r = 0; r < 4; ++r) {
      short hh_, ll_; split_hl(h1v[r], hh_, ll_);
      const int row = 4 * g + r;
      l1h[row * 32 + 16 + col] = hh_;
      l1l[row * 32 + 16 + col] = ll_;
      l2h[row * 32 + col]      = hh_;
      l2l[row * 32 + col]      = ll_;
    }
    lds_fence();
  }

  // ---- merged loop: LSTM1(i) || LSTM2(i-1) ----
  for (int i = 1; i < NT; ++i) {
    bf16x8 A1  = *(const bf16x8*)aL1h;
    bf16x8 A3  = *(const bf16x8*)aL1l;
    bf16x8 A1c = *(const bf16x8*)aL2h;
    bf16x8 A3c = *(const bf16x8*)aL2l;
    const int tn = (i + 1 < NT) ? (i + 1) : (NT - 1);
    f32x4 xa = *(const f32x4*)(xrow + tn * NF);
    f32x4 xb = *(const f32x4*)(xrow + tn * NF + 4);

    f32x4 z[4], y[4];
#pragma unroll
    for (int n = 0; n < 4; ++n) {
      f32x4 zi = bias1v[n];
      zi = MFMA16(A1, B1a[n], zi, 0, 0, 0);
      zi = MFMA16(A1, B2a[n], zi, 0, 0, 0);
      zi = MFMA16(A3, B1a[n], zi, 0, 0, 0);
      z[n] = zi;
      f32x4 yi = bias2v[n];
      yi = MFMA16(A1c, B1b[n], yi, 0, 0, 0);
      yi = MFMA16(A1c, B2b[n], yi, 0, 0, 0);
      yi = MFMA16(A3c, B2b[n], yi, 0, 0, 0);
      y[n] = yi;
    }
    // NOTE: third LSTM2 MFMA must be A3c@B1b (lo-h against hi-W); fix below.
    // (kept explicit to preserve the algebra)
#pragma unroll
    for (int n = 0; n < 4; ++n) {
      // correct the y chain: recompute with proper operand pairing
      f32x4 yi = bias2v[n];
      yi = MFMA16(A1c, B1b[n], yi, 0, 0, 0);
      yi = MFMA16(A1c, B2b[n], yi, 0, 0, 0);
      yi = MFMA16(A3c, B1b[n], yi, 0, 0, 0);
      y[n] = yi;
    }
#pragma unroll
    for (int r = 0; r < 4; ++r) {
      float ig = sigmoidf_(z[0][r]);
      float fg = sigmoidf_(z[1][r]);
      float gg = fmaxf(z[2][r], 0.f);
      float og = sigmoidf_(z[3][r]);
      float cc = fg * c1[r] + ig * gg;
      c1[r] = cc;
      h1v[r] = og * fmaxf(cc, 0.f);
    }
#pragma unroll
    for (int r = 0; r < 4; ++r) {
      float ig = sigmoidf_(y[0][r]);
      float fg = sigmoidf_(y[1][r]);
      float gg = fmaxf(y[2][r], 0.f);
      float og = sigmoidf_(y[3][r]);
      float cc = fg * c2[r] + ig * gg;
      c2[r] = cc;
      h2v[r] = og * fmaxf(cc, 0.f);
    }
    cbar();
    // stash x(i+1)
    bf16x8 xh8, xl8;
#pragma unroll
    for (int j = 0; j < 4; ++j) {
      short h, l;
      split_hl(xa[j], h, l); xh8[j] = h;     xl8[j] = l;
      split_hl(xb[j], h, l); xh8[4 + j] = h; xl8[4 + j] = l;
    }
    if (g == 0)      *(bf16x8*)(l1h + col * 32)     = xh8;
    else if (g == 1) *(bf16x8*)(l1h + col * 32 + 8) = xl8;
    // write h1(i), h2(i-1)
#pragma unroll
    for (int r = 0; r < 4; ++r) {
      short hh_, ll_; split_hl(h1v[r], hh_, ll_);
      const int row = 4 * g + r;
      l1h[row * 32 + 16 + col] = hh_;
      l1l[row * 32 + 16 + col] = ll_;
      l2h[row * 32 + col]      = hh_;
      l2l[row * 32 + col]      = ll_;
    }
#pragma unroll
    for (int r = 0; r < 4; ++r) {
      short hh_, ll_; split_hl(h2v[r], hh_, ll_);
      const int row = 4 * g + r;
      l2h[row * 32 + 16 + col] = hh_;
      l2l[row * 32 + 16 + col] = ll_;
    }
    lds_fence();
  }

  // ---- epilogue: LSTM2(63) ----
  {
    bf16x8 A1c = *(const bf16x8*)aL2h;
    bf16x8 A3c = *(const bf16x8*)aL2l;
    f32x4 y[4];
#pragma unroll
    for (int n = 0; n < 4; ++n) {
      f32x4 yi = bias2v[n];
      yi = MFMA16(A1c, B1b[n], yi, 0, 0, 0);
      yi = MFMA16(A1c, B2b[n], yi, 0, 0, 0);
      yi = MFMA16(A3c, B1b[n], yi, 0, 0, 0);
      y[n] = yi;
    }
#pragma unroll
    for (int r = 0; r < 4; ++r) {
      float ig = sigmoidf_(y[0][r]);
      float fg = sigmoidf_(y[1][r]);
      float gg = fmaxf(y[2][r], 0.f);
      float og = sigmoidf_(y[3][r]);
      float cc = fg * c2[r] + ig * gg;
      c2[r] = cc;
      h2v[r] = og * fmaxf(cc, 0.f);
    }
    cbar();
#pragma unroll
    for (int r = 0; r < 4; ++r) {
      short hh_, ll_; split_hl(h2v[r], hh_, ll_);
      const int row = 4 * g + r;
      l2h[row * 32 + 16 + col] = hh_;
      l2l[row * 32 + 16 + col] = ll_;
    }
    lds_fence();
  }

  // ================= FC head =================
  // A_fc = [h2h(16) | h2l(16)] read from L2A slots 16..31
  const short* afp = ((g < 2) ? l2h : l2l) + col * 32 + 16 + (g & 1) * 8;
  bf16x8 Afc = *(const bf16x8*)afp;

  f32x4 acc2[2];
#pragma unroll
  for (int nn = 0; nn < 2; ++nn) {
    float bb = bfc2[16 * nn + col];
    acc2[nn] = (f32x4){bb, bb, bb, bb};
  }

  // depth-1 weight prefetch (raw f32 in regs, split in-loop)
  float cw1[16], cw2[16];
#pragma unroll
  for (int j = 0; j < 8; ++j) {
    const int kr = (8 * g + j) & 15;
    cw1[j]     = Wfc1[kr * 512 + col];
    cw1[8 + j] = Wfc1[kr * 512 + 16 + col];
    cw2[j]     = Wfc2[(8 * g + j) * 32 + col];
    cw2[8 + j] = Wfc2[(8 * g + j) * 32 + 16 + col];
  }

  for (int kc = 0; kc < 16; ++kc) {
    const int kn = (kc < 15) ? kc + 1 : 15;
    float nw1[16], nw2[16];
#pragma unroll
    for (int j = 0; j < 8; ++j) {
      const int kr = (8 * g + j) & 15;
      nw1[j]     = Wfc1[kr * 512 + 32 * kn + col];
      nw1[8 + j] = Wfc1[kr * 512 + 32 * kn + 16 + col];
      nw2[j]     = Wfc2[(size_t)(32 * kn + 8 * g + j) * 32 + col];
      nw2[8 + j] = Wfc2[(size_t)(32 * kn + 8 * g + j) * 32 + 16 + col];
    }
    // FC1 tiles (cols 32kc..32kc+31)
#pragma unroll
    for (int s = 0; s < 2; ++s) {
      bf16x8 Bh, Bl;
#pragma unroll
      for (int j = 0; j < 8; ++j) {
        short h, l;
        split_hl(cw1[8 * s + j], h, l);
        Bh[j] = h; Bl[j] = l;
      }
      float bb = bfc1[32 * kc + 16 * s + col];
      f32x4 acc = (f32x4){bb, bb, bb, bb};
      acc = MFMA16(Afc, Bh, acc, 0, 0, 0);
      acc = MFMA16(Afc, Bl, acc, 0, 0, 0);
#pragma unroll
      for (int r = 0; r < 4; ++r) {
        short h, l;
        split_hl(fmaxf(acc[r], 0.f), h, l);
        cfh[(4 * g + r) * 40 + 16 * s + col] = h;
        cfl[(4 * g + r) * 40 + 16 * s + col] = l;
      }
    }
    lds_fence();
    bf16x8 Ah = *(const bf16x8*)(cfh + col * 40 + 8 * g);
    bf16x8 Al = *(const bf16x8*)(cfl + col * 40 + 8 * g);
#pragma unroll
    for (int nn = 0; nn < 2; ++nn) {
      bf16x8 Bh, Bl;
#pragma unroll
      for (int j = 0; j < 8; ++j) {
        short h, l;
        split_hl(cw2[8 * nn + j], h, l);
        Bh[j] = h; Bl[j] = l;
      }
      acc2[nn] = MFMA16(Ah, Bh, acc2[nn], 0, 0, 0);
      acc2[nn] = MFMA16(Al, Bh, acc2[nn], 0, 0, 0);
      acc2[nn] = MFMA16(Ah, Bl, acc2[nn], 0, 0, 0);
    }
    lds_fence();   // WAR: next kc overwrites cfh/cfl
#pragma unroll
    for (int q = 0; q < 16; ++q) { cw1[q] = nw1[q]; cw2[q] = nw2[q]; }
  }

#pragma unroll
  for (int nn = 0; nn < 2; ++nn)
#pragma unroll
    for (int r = 0; r < 4; ++r)
      out[(size_t)(base + 4 * g + r) * 32 + 16 * nn + col] = acc2[nn][r];
}

extern "C" void kernel_launch(void* const* d_in, const int* in_sizes, int n_in,
                              void* d_out, int out_size, void* d_ws, size_t ws_size,
                              hipStream_t stream) {
  const float* x    = (const float*)d_in[0];
  const float* W1   = (const float*)d_in[1];
  const float* U1   = (const float*)d_in[2];
  const float* b1   = (const float*)d_in[3];
  const float* W2   = (const float*)d_in[4];
  const float* U2   = (const float*)d_in[5];
  const float* b2   = (const float*)d_in[6];
  const float* Wfc1 = (const float*)d_in[7];
  const float* bfc1 = (const float*)d_in[8];
  const float* Wfc2 = (const float*)d_in[9];
  const float* bfc2 = (const float*)d_in[10];

  lstm_fused<<<dim3(512), dim3(256), 0, stream>>>(
      x, W1, U1, b1, W2, U2, b2, Wfc1, bfc1, Wfc2, bfc2, (float*)d_out);
}

// Round 4
// 235.670 us; speedup vs baseline: 1.0698x; 1.0698x over previous
//
#include <hip/hip_runtime.h>
#include <stdint.h>

// Fused 2-layer LSTM (B=32768, T=64, F=8, H=16) + FC(16->512,relu) + FC(512->32)
// SWAPPED-OPERAND design: A=weights [gate][k], B=inputs [k][batch], C=z^T.
// Weight registers identical to previous (verified) kernel; only MFMA arg order
// swaps. Recurrent h handoff = pure lane permutation (8 ds_bpermute per h),
// NO LDS / NO fences in the 64-step loop. bf16 hi/lo split, fp32 accum.

#define NT 64
#define NF 8

typedef __attribute__((ext_vector_type(8))) short bf16x8;
typedef __attribute__((ext_vector_type(4))) float f32x4;
typedef __attribute__((ext_vector_type(2))) unsigned int u32x2;
typedef __attribute__((ext_vector_type(4))) unsigned int u32x4;

#define MFMA16 __builtin_amdgcn_mfma_f32_16x16x32_bf16

static __device__ __forceinline__ uint32_t bfraw(float f) {
  uint32_t u = __float_as_uint(f);
  return u + 0x7FFFu + ((u >> 16) & 1u);   // RTNE; low 16 bits are garbage
}
static __device__ __forceinline__ float hipart(uint32_t raw) {
  return __uint_as_float(raw & 0xFFFF0000u);
}
// pack pair: low16 = bf16(a), high16 = bf16(b); plus lo-residual pack
static __device__ __forceinline__ void pack_hl(float a, float b,
                                               uint32_t& hi, uint32_t& lo) {
  uint32_t ra = bfraw(a), rb = bfraw(b);
  hi = (rb & 0xFFFF0000u) | (ra >> 16);
  float la = a - hipart(ra);
  float lb = b - hipart(rb);
  uint32_t rla = bfraw(la), rlb = bfraw(rb == 0u ? 0.f : lb); // keep simple: see below
  rlb = bfraw(lb);
  lo = (rlb & 0xFFFF0000u) | (rla >> 16);
}
static __device__ __forceinline__ void split_hl(float f, short& hi, short& lo) {
  uint32_t r = bfraw(f);
  hi = (short)(r >> 16);
  float res = f - hipart(r);
  lo = (short)(bfraw(res) >> 16);
}
static __device__ __forceinline__ float sigmoidf_(float v) {
  return __builtin_amdgcn_rcpf(1.0f + __expf(-v));
}
static __device__ __forceinline__ bf16x8 asbf(u32x4 w) {
  union { u32x4 u; bf16x8 b; } c; c.u = w; return c.b;
}
static __device__ __forceinline__ uint32_t bperm(int addr, uint32_t v) {
  return (uint32_t)__builtin_amdgcn_ds_bpermute(addr, (int)v);
}
static __device__ __forceinline__ void lds_fence() {
  asm volatile("s_waitcnt lgkmcnt(0)" ::: "memory");
}

__global__ __launch_bounds__(256, 2) void lstm_fused(
    const float* __restrict__ x,
    const float* __restrict__ W1, const float* __restrict__ U1, const float* __restrict__ b1,
    const float* __restrict__ W2, const float* __restrict__ U2, const float* __restrict__ b2,
    const float* __restrict__ Wfc1, const float* __restrict__ bfc1,
    const float* __restrict__ Wfc2, const float* __restrict__ bfc2,
    float* __restrict__ out)
{
  const int tid  = threadIdx.x;
  const int lane = tid & 63;
  const int wv   = tid >> 6;
  const int col  = lane & 15;   // batch column (B-frag N / C-frag col)
  const int g    = lane >> 4;   // K-group (slots 8g..8g+7) / C-row group
  const int base = (blockIdx.x * 4 + wv) * 16;

  // LDS only for the FC1->FC2 staging: per wave [hi/lo][16 col][32 u16] = 2KB
  __shared__ __align__(16) short cf[4][2][512];
  short* const cfh = &cf[wv][0][0];
  short* const cfl = &cf[wv][1][0];

  // ---- static weight fragments (identical values to previous kernel) ----
  // Now used in the MFMA *A* position: A[m=gate][k], lane holds m=col, k=8g+j.
  // LSTM1: B1a = [W1h; W1h; U1h], B2a = [W1l; 0; U1l]
  // LSTM2: B1b = [W2h; U2h],      B2b = [W2l; U2l]
  bf16x8 B1a[4], B2a[4], B1b[4], B2b[4];
#pragma unroll
  for (int n = 0; n < 4; ++n) {
    const int c = 16 * n + col;
#pragma unroll
    for (int j = 0; j < 8; ++j) {
      const int k = 8 * g + j;
      short h, l;
      if (k < 8)       { split_hl(W1[k * 64 + c], h, l);        B1a[n][j] = h; B2a[n][j] = l; }
      else if (k < 16) { split_hl(W1[(k - 8) * 64 + c], h, l);  B1a[n][j] = h; B2a[n][j] = 0; }
      else             { split_hl(U1[(k - 16) * 64 + c], h, l); B1a[n][j] = h; B2a[n][j] = l; }
      short h2, l2;
      if (k < 16) split_hl(W2[k * 64 + c], h2, l2);
      else        split_hl(U2[(k - 16) * 64 + c], h2, l2);
      B1b[n][j] = h2; B2b[n][j] = l2;
    }
  }

  // biases: C rows are GATES now -> bias element = b[16n + 4g + r]
  f32x4 bias1v[4], bias2v[4];
#pragma unroll
  for (int n = 0; n < 4; ++n) {
    bias1v[n] = *(const f32x4*)(b1 + 16 * n + 4 * g);
    bias2v[n] = *(const f32x4*)(b2 + 16 * n + 4 * g);
  }

  // bpermute source lanes: srcA = 32*(g&1)+col, srcB = srcA+16 (byte addrs *4)
  const int addrA = ((g & 1) * 32 + col) * 4;
  const int addrB = addrA + 64;

  f32x4 c1 = {0.f, 0.f, 0.f, 0.f};
  f32x4 c2 = {0.f, 0.f, 0.f, 0.f};
  // pulled h fragments (u32 = bf16 pair); [A.p01, A.p23, B.p01, B.p23]
  uint32_t h1ph[4] = {0,0,0,0}, h1pl[4] = {0,0,0,0};
  uint32_t h2ph[4] = {0,0,0,0}, h2pl[4] = {0,0,0,0};

  const float* xrow = x + (size_t)(base + col) * (NT * NF);
  f32x4 xa = *(const f32x4*)(xrow);
  f32x4 xb = *(const f32x4*)(xrow + 4);

  // ================= merged recurrent loop: LSTM1(i) || LSTM2(i-1) ==========
  for (int i = 0; i < NT; ++i) {
    // L2 B-frags from OLD pulls (h1(i-1), h2(i-2)) -- before overwrite
    u32x4 l2b1w, l2b3w;
#pragma unroll
    for (int q = 0; q < 4; ++q) {
      l2b1w[q] = (g < 2) ? h1ph[q] : h2ph[q];
      l2b3w[q] = (g < 2) ? h1pl[q] : h2pl[q];
    }
    // split current x into hi/lo packed words
    uint32_t xh[4], xl[4];
    pack_hl(xa[0], xa[1], xh[0], xl[0]);
    pack_hl(xa[2], xa[3], xh[1], xl[1]);
    pack_hl(xb[0], xb[1], xh[2], xl[2]);
    pack_hl(xb[2], xb[3], xh[3], xl[3]);
    // prefetch next x
    if (i + 1 < NT) {
      xa = *(const f32x4*)(xrow + (i + 1) * NF);
      xb = *(const f32x4*)(xrow + (i + 1) * NF + 4);
    }
    // L1 B-frags: B1 = [xh | xl | h1h], B3 = [0 | 0 | h1l]
    u32x4 l1b1w, l1b3w;
#pragma unroll
    for (int q = 0; q < 4; ++q) {
      uint32_t xw = (g == 0) ? xh[q] : xl[q];
      l1b1w[q] = (g < 2) ? xw : h1ph[q];
      l1b3w[q] = (g < 2) ? 0u : h1pl[q];
    }
    bf16x8 L1B1 = asbf(l1b1w), L1B3 = asbf(l1b3w);
    bf16x8 L2B1 = asbf(l2b1w), L2B3 = asbf(l2b3w);

    f32x4 z[4], y[4];
#pragma unroll
    for (int n = 0; n < 4; ++n) {
      f32x4 zi = MFMA16(B1a[n], L1B1, bias1v[n], 0, 0, 0);
      zi = MFMA16(B2a[n], L1B1, zi, 0, 0, 0);
      zi = MFMA16(B1a[n], L1B3, zi, 0, 0, 0);
      z[n] = zi;
      f32x4 yi = MFMA16(B1b[n], L2B1, bias2v[n], 0, 0, 0);
      yi = MFMA16(B2b[n], L2B1, yi, 0, 0, 0);
      yi = MFMA16(B1b[n], L2B3, yi, 0, 0, 0);
      y[n] = yi;
    }

    f32x4 h1v, h2v;
#pragma unroll
    for (int r = 0; r < 4; ++r) {
      float ig = sigmoidf_(z[0][r]);
      float fg = sigmoidf_(z[1][r]);
      float gg = fmaxf(z[2][r], 0.f);
      float og = sigmoidf_(z[3][r]);
      float cc = fg * c1[r] + ig * gg;
      c1[r] = cc;
      h1v[r] = og * fmaxf(cc, 0.f);
    }
    if (i != 0) {
#pragma unroll
      for (int r = 0; r < 4; ++r) {
        float ig = sigmoidf_(y[0][r]);
        float fg = sigmoidf_(y[1][r]);
        float gg = fmaxf(y[2][r], 0.f);
        float og = sigmoidf_(y[3][r]);
        float cc = fg * c2[r] + ig * gg;
        c2[r] = cc;
        h2v[r] = og * fmaxf(cc, 0.f);
      }
    } else {
      h2v = (f32x4){0.f, 0.f, 0.f, 0.f};
    }

    // pack + bpermute h1(i) -> new pulls
    {
      uint32_t p01h, p01l, p23h, p23l;
      pack_hl(h1v[0], h1v[1], p01h, p01l);
      pack_hl(h1v[2], h1v[3], p23h, p23l);
      h1ph[0] = bperm(addrA, p01h); h1ph[1] = bperm(addrA, p23h);
      h1ph[2] = bperm(addrB, p01h); h1ph[3] = bperm(addrB, p23h);
      h1pl[0] = bperm(addrA, p01l); h1pl[1] = bperm(addrA, p23l);
      h1pl[2] = bperm(addrB, p01l); h1pl[3] = bperm(addrB, p23l);
    }
    // pack + bpermute h2(i-1) -> new pulls
    {
      uint32_t p01h, p01l, p23h, p23l;
      pack_hl(h2v[0], h2v[1], p01h, p01l);
      pack_hl(h2v[2], h2v[3], p23h, p23l);
      h2ph[0] = bperm(addrA, p01h); h2ph[1] = bperm(addrA, p23h);
      h2ph[2] = bperm(addrB, p01h); h2ph[3] = bperm(addrB, p23h);
      h2pl[0] = bperm(addrA, p01l); h2pl[1] = bperm(addrA, p23l);
      h2pl[2] = bperm(addrB, p01l); h2pl[3] = bperm(addrB, p23l);
    }
  }

  // ---- epilogue: LSTM2(63) ----
  {
    u32x4 b1w, b3w;
#pragma unroll
    for (int q = 0; q < 4; ++q) {
      b1w[q] = (g < 2) ? h1ph[q] : h2ph[q];
      b3w[q] = (g < 2) ? h1pl[q] : h2pl[q];
    }
    bf16x8 L2B1 = asbf(b1w), L2B3 = asbf(b3w);
    f32x4 y[4];
#pragma unroll
    for (int n = 0; n < 4; ++n) {
      f32x4 yi = MFMA16(B1b[n], L2B1, bias2v[n], 0, 0, 0);
      yi = MFMA16(B2b[n], L2B1, yi, 0, 0, 0);
      yi = MFMA16(B1b[n], L2B3, yi, 0, 0, 0);
      y[n] = yi;
    }
    f32x4 h2v;
#pragma unroll
    for (int r = 0; r < 4; ++r) {
      float ig = sigmoidf_(y[0][r]);
      float fg = sigmoidf_(y[1][r]);
      float gg = fmaxf(y[2][r], 0.f);
      float og = sigmoidf_(y[3][r]);
      float cc = fg * c2[r] + ig * gg;
      c2[r] = cc;
      h2v[r] = og * fmaxf(cc, 0.f);
    }
    uint32_t p01h, p01l, p23h, p23l;
    pack_hl(h2v[0], h2v[1], p01h, p01l);
    pack_hl(h2v[2], h2v[3], p23h, p23l);
    h2ph[0] = bperm(addrA, p01h); h2ph[1] = bperm(addrA, p23h);
    h2ph[2] = bperm(addrB, p01h); h2ph[3] = bperm(addrB, p23h);
    h2pl[0] = bperm(addrA, p01l); h2pl[1] = bperm(addrA, p23l);
    h2pl[2] = bperm(addrB, p01l); h2pl[3] = bperm(addrB, p23l);
  }

  // ================= FC head (swapped layout) =================
  // B-frag: K = [h2hi(16) | h2lo(16)], lane(col,g): g<2 -> hi pulls, g>=2 -> lo
  u32x4 bwf;
#pragma unroll
  for (int q = 0; q < 4; ++q) bwf[q] = (g < 2) ? h2ph[q] : h2pl[q];
  bf16x8 Bfc = asbf(bwf);

  f32x4 acc2[2];
#pragma unroll
  for (int nn = 0; nn < 2; ++nn)
    acc2[nn] = *(const f32x4*)(bfc2 + 16 * nn + 4 * g);

  for (int kc = 0; kc < 16; ++kc) {
#pragma unroll
    for (int t = 0; t < 2; ++t) {
      const int mt = 2 * kc + t;
      // A-frag = [Wfc1h;Wfc1h] (dup along k) and [Wfc1l;Wfc1l]
      bf16x8 A1h, A1l;
#pragma unroll
      for (int j = 0; j < 8; ++j) {
        float w = Wfc1[((8 * g + j) & 15) * 512 + 16 * mt + col];
        short h, l; split_hl(w, h, l);
        A1h[j] = h; A1l[j] = l;
      }
      f32x4 bv = *(const f32x4*)(bfc1 + 16 * mt + 4 * g);
      f32x4 acc = MFMA16(A1h, Bfc, bv, 0, 0, 0);
      acc = MFMA16(A1l, Bfc, acc, 0, 0, 0);
      // relu + pack, stage to LDS: [col][fcrow32] u16
      uint32_t q01h, q01l, q23h, q23l;
      pack_hl(fmaxf(acc[0], 0.f), fmaxf(acc[1], 0.f), q01h, q01l);
      pack_hl(fmaxf(acc[2], 0.f), fmaxf(acc[3], 0.f), q23h, q23l);
      *(u32x2*)((char*)cfh + col * 64 + 32 * t + 8 * g) = (u32x2){q01h, q23h};
      *(u32x2*)((char*)cfl + col * 64 + 32 * t + 8 * g) = (u32x2){q01l, q23l};
    }
    lds_fence();
    bf16x8 Bh = *(const bf16x8*)((char*)cfh + col * 64 + 16 * g);
    bf16x8 Bl = *(const bf16x8*)((char*)cfl + col * 64 + 16 * g);
#pragma unroll
    for (int nn = 0; nn < 2; ++nn) {
      bf16x8 A2h, A2l;
#pragma unroll
      for (int j = 0; j < 8; ++j) {
        float w = Wfc2[(size_t)(32 * kc + 8 * g + j) * 32 + 16 * nn + col];
        short h, l; split_hl(w, h, l);
        A2h[j] = h; A2l[j] = l;
      }
      acc2[nn] = MFMA16(A2h, Bh, acc2[nn], 0, 0, 0);
      acc2[nn] = MFMA16(A2h, Bl, acc2[nn], 0, 0, 0);
      acc2[nn] = MFMA16(A2l, Bh, acc2[nn], 0, 0, 0);
    }
    lds_fence();   // WAR: next kc overwrites staging
  }

  // out[b][32]: lane(col,g) holds rows 16nn+4g+r of batch base+col
#pragma unroll
  for (int nn = 0; nn < 2; ++nn)
    *(f32x4*)(out + (size_t)(base + col) * 32 + 16 * nn + 4 * g) = acc2[nn];
}

extern "C" void kernel_launch(void* const* d_in, const int* in_sizes, int n_in,
                              void* d_out, int out_size, void* d_ws, size_t ws_size,
                              hipStream_t stream) {
  const float* x    = (const float*)d_in[0];
  const float* W1   = (const float*)d_in[1];
  const float* U1   = (const float*)d_in[2];
  const float* b1   = (const float*)d_in[3];
  const float* W2   = (const float*)d_in[4];
  const float* U2   = (const float*)d_in[5];
  const float* b2   = (const float*)d_in[6];
  const float* Wfc1 = (const float*)d_in[7];
  const float* bfc1 = (const float*)d_in[8];
  const float* Wfc2 = (const float*)d_in[9];
  const float* bfc2 = (const float*)d_in[10];

  lstm_fused<<<dim3(512), dim3(256), 0, stream>>>(
      x, W1, U1, b1, W2, U2, b2, Wfc1, bfc1, Wfc2, bfc2, (float*)d_out);
}

// Round 7
// 219.823 us; speedup vs baseline: 1.1469x; 1.0721x over previous
//
#include <hip/hip_runtime.h>
#include <stdint.h>

// Fused 2-layer LSTM (B=32768, T=64, F=8, H=16) + FC(16->512,relu) + FC(512->32)
// SWAPPED-OPERAND design: A=weights [gate][k], B=inputs [k][batch], C=z^T.
// Recurrent h handoff = 16 ds_bpermute/step, no LDS fences in recurrent loop.
// bf16 hi/lo split (Dekker) with fp32 MFMA accum.
// R5: v_cvt_pk_bf16_f32 hardware packing (1 op vs ~8), bperm/VALU overlap
// reorder, FC staging stride 80B. Attacking VALU issue count (62% busy @ R4).

#define NT 64
#define NF 8

typedef __attribute__((ext_vector_type(8))) short bf16x8;
typedef __attribute__((ext_vector_type(4))) float f32x4;
typedef __attribute__((ext_vector_type(2))) unsigned int u32x2;
typedef __attribute__((ext_vector_type(4))) unsigned int u32x4;

#define MFMA16 __builtin_amdgcn_mfma_f32_16x16x32_bf16

// packed bf16 pair: low16 = bf16(a), high16 = bf16(b). RNE in HW.
static __device__ __forceinline__ uint32_t cvt_pk(float a, float b) {
  uint32_t r;
  asm("v_cvt_pk_bf16_f32 %0, %1, %2" : "=v"(r) : "v"(a), "v"(b));
  return r;
}
// hi word + lo(residual) word for a pair: 6 VALU ops total
static __device__ __forceinline__ void pack_hl(float a, float b,
                                               uint32_t& hi, uint32_t& lo) {
  hi = cvt_pk(a, b);
  float ha = __uint_as_float(hi << 16);          // bf16(a) as f32
  float hb = __uint_as_float(hi & 0xFFFF0000u);  // bf16(b) as f32
  lo = cvt_pk(a - ha, b - hb);
}
static __device__ __forceinline__ void split_hl(float f, short& hi, short& lo) {
  uint32_t w = cvt_pk(f, 0.f);
  hi = (short)(w & 0xFFFFu);
  float hf = __uint_as_float(w << 16);
  uint32_t wl = cvt_pk(f - hf, 0.f);
  lo = (short)(wl & 0xFFFFu);
}
static __device__ __forceinline__ float sigmoidf_(float v) {
  return __builtin_amdgcn_rcpf(1.0f + __expf(-v));
}
static __device__ __forceinline__ bf16x8 asbf(u32x4 w) {
  union { u32x4 u; bf16x8 b; } c; c.u = w; return c.b;
}
static __device__ __forceinline__ uint32_t bperm(int addr, uint32_t v) {
  return (uint32_t)__builtin_amdgcn_ds_bpermute(addr, (int)v);
}
static __device__ __forceinline__ void lds_fence() {
  asm volatile("s_waitcnt lgkmcnt(0)" ::: "memory");
}

__global__ __launch_bounds__(256, 2) void lstm_fused(
    const float* __restrict__ x,
    const float* __restrict__ W1, const float* __restrict__ U1, const float* __restrict__ b1,
    const float* __restrict__ W2, const float* __restrict__ U2, const float* __restrict__ b2,
    const float* __restrict__ Wfc1, const float* __restrict__ bfc1,
    const float* __restrict__ Wfc2, const float* __restrict__ bfc2,
    float* __restrict__ out)
{
  const int tid  = threadIdx.x;
  const int lane = tid & 63;
  const int wv   = tid >> 6;
  const int col  = lane & 15;   // batch column (B-frag N / C-frag col)
  const int g    = lane >> 4;   // K-group (slots 8g..8g+7) / C-row group
  const int base = (blockIdx.x * 4 + wv) * 16;

  // FC1->FC2 staging: per wave, per hi/lo, 16 cols x 80B (stride 80B: 16B
  // aligned for b128, banks spread by 20 per col -> <=2-way conflicts)
  __shared__ __align__(16) char cf[4][2][16 * 80];
  char* const cfh = &cf[wv][0][0];
  char* const cfl = &cf[wv][1][0];

  // ---- static weight fragments (A-position: A[m=gate][k]) ----
  // LSTM1: B1a = [W1h; W1h; U1h], B2a = [W1l; 0; U1l]
  // LSTM2: B1b = [W2h; U2h],      B2b = [W2l; U2l]
  bf16x8 B1a[4], B2a[4], B1b[4], B2b[4];
#pragma unroll
  for (int n = 0; n < 4; ++n) {
    const int c = 16 * n + col;
#pragma unroll
    for (int j = 0; j < 8; ++j) {
      const int k = 8 * g + j;
      short h, l;
      if (k < 8)       { split_hl(W1[k * 64 + c], h, l);        B1a[n][j] = h; B2a[n][j] = l; }
      else if (k < 16) { split_hl(W1[(k - 8) * 64 + c], h, l);  B1a[n][j] = h; B2a[n][j] = 0; }
      else             { split_hl(U1[(k - 16) * 64 + c], h, l); B1a[n][j] = h; B2a[n][j] = l; }
      short h2, l2;
      if (k < 16) split_hl(W2[k * 64 + c], h2, l2);
      else        split_hl(U2[(k - 16) * 64 + c], h2, l2);
      B1b[n][j] = h2; B2b[n][j] = l2;
    }
  }

  // biases: C rows are gates -> element b[16n + 4g + r]
  f32x4 bias1v[4], bias2v[4];
#pragma unroll
  for (int n = 0; n < 4; ++n) {
    bias1v[n] = *(const f32x4*)(b1 + 16 * n + 4 * g);
    bias2v[n] = *(const f32x4*)(b2 + 16 * n + 4 * g);
  }

  // bpermute source lanes: srcA = 32*(g&1)+col, srcB = srcA+16 (byte addr *4)
  const int addrA = ((g & 1) * 32 + col) * 4;
  const int addrB = addrA + 64;

  f32x4 c1 = {0.f, 0.f, 0.f, 0.f};
  f32x4 c2 = {0.f, 0.f, 0.f, 0.f};
  uint32_t h1ph[4] = {0,0,0,0}, h1pl[4] = {0,0,0,0};
  uint32_t h2ph[4] = {0,0,0,0}, h2pl[4] = {0,0,0,0};

  const float* xrow = x + (size_t)(base + col) * (NT * NF);
  f32x4 xa = *(const f32x4*)(xrow);
  f32x4 xb = *(const f32x4*)(xrow + 4);

  // ================= merged recurrent loop: LSTM1(i) || LSTM2(i-1) ==========
  for (int i = 0; i < NT; ++i) {
    // L2 B-frags from OLD pulls (h1(i-1), h2(i-2)) -- before overwrite
    u32x4 l2b1w, l2b3w;
#pragma unroll
    for (int q = 0; q < 4; ++q) {
      l2b1w[q] = (g < 2) ? h1ph[q] : h2ph[q];
      l2b3w[q] = (g < 2) ? h1pl[q] : h2pl[q];
    }
    // split current x into hi/lo packed words (cvt_pk: 6 ops/pair)
    uint32_t xh[4], xl[4];
    pack_hl(xa[0], xa[1], xh[0], xl[0]);
    pack_hl(xa[2], xa[3], xh[1], xl[1]);
    pack_hl(xb[0], xb[1], xh[2], xl[2]);
    pack_hl(xb[2], xb[3], xh[3], xl[3]);
    // prefetch next x (independent; overlaps everything below)
    if (i + 1 < NT) {
      xa = *(const f32x4*)(xrow + (i + 1) * NF);
      xb = *(const f32x4*)(xrow + (i + 1) * NF + 4);
    }
    // L1 B-frags: B1 = [xh | xl | h1h], B3 = [0 | 0 | h1l]
    u32x4 l1b1w, l1b3w;
#pragma unroll
    for (int q = 0; q < 4; ++q) {
      uint32_t xw = (g == 0) ? xh[q] : xl[q];
      l1b1w[q] = (g < 2) ? xw : h1ph[q];
      l1b3w[q] = (g < 2) ? 0u : h1pl[q];
    }
    bf16x8 L1B1 = asbf(l1b1w), L1B3 = asbf(l1b3w);
    bf16x8 L2B1 = asbf(l2b1w), L2B3 = asbf(l2b3w);

    f32x4 z[4], y[4];
#pragma unroll
    for (int n = 0; n < 4; ++n) {
      f32x4 zi = MFMA16(B1a[n], L1B1, bias1v[n], 0, 0, 0);
      zi = MFMA16(B2a[n], L1B1, zi, 0, 0, 0);
      zi = MFMA16(B1a[n], L1B3, zi, 0, 0, 0);
      z[n] = zi;
      f32x4 yi = MFMA16(B1b[n], L2B1, bias2v[n], 0, 0, 0);
      yi = MFMA16(B2b[n], L2B1, yi, 0, 0, 0);
      yi = MFMA16(B1b[n], L2B3, yi, 0, 0, 0);
      y[n] = yi;
    }

    // ---- LSTM1 gates -> h1(i), pack, ISSUE bpermutes early ----
    f32x4 h1v;
#pragma unroll
    for (int r = 0; r < 4; ++r) {
      float ig = sigmoidf_(z[0][r]);
      float fg = sigmoidf_(z[1][r]);
      float gg = fmaxf(z[2][r], 0.f);
      float og = sigmoidf_(z[3][r]);
      float cc = fg * c1[r] + ig * gg;
      c1[r] = cc;
      h1v[r] = og * fmaxf(cc, 0.f);
    }
    {
      uint32_t p01h, p01l, p23h, p23l;
      pack_hl(h1v[0], h1v[1], p01h, p01l);
      pack_hl(h1v[2], h1v[3], p23h, p23l);
      h1ph[0] = bperm(addrA, p01h); h1ph[1] = bperm(addrA, p23h);
      h1ph[2] = bperm(addrB, p01h); h1ph[3] = bperm(addrB, p23h);
      h1pl[0] = bperm(addrA, p01l); h1pl[1] = bperm(addrA, p23l);
      h1pl[2] = bperm(addrB, p01l); h1pl[3] = bperm(addrB, p23l);
    }

    // ---- LSTM2 gates (VALU overlaps h1 bperm latency) -> h2(i-1) ----
    f32x4 h2v;
    if (i != 0) {
#pragma unroll
      for (int r = 0; r < 4; ++r) {
        float ig = sigmoidf_(y[0][r]);
        float fg = sigmoidf_(y[1][r]);
        float gg = fmaxf(y[2][r], 0.f);
        float og = sigmoidf_(y[3][r]);
        float cc = fg * c2[r] + ig * gg;
        c2[r] = cc;
        h2v[r] = og * fmaxf(cc, 0.f);
      }
    } else {
      h2v = (f32x4){0.f, 0.f, 0.f, 0.f};
    }
    {
      uint32_t p01h, p01l, p23h, p23l;
      pack_hl(h2v[0], h2v[1], p01h, p01l);
      pack_hl(h2v[2], h2v[3], p23h, p23l);
      h2ph[0] = bperm(addrA, p01h); h2ph[1] = bperm(addrA, p23h);
      h2ph[2] = bperm(addrB, p01h); h2ph[3] = bperm(addrB, p23h);
      h2pl[0] = bperm(addrA, p01l); h2pl[1] = bperm(addrA, p23l);
      h2pl[2] = bperm(addrB, p01l); h2pl[3] = bperm(addrB, p23l);
    }
  }

  // ---- epilogue: LSTM2(63) ----
  {
    u32x4 b1w, b3w;
#pragma unroll
    for (int q = 0; q < 4; ++q) {
      b1w[q] = (g < 2) ? h1ph[q] : h2ph[q];
      b3w[q] = (g < 2) ? h1pl[q] : h2pl[q];
    }
    bf16x8 L2B1 = asbf(b1w), L2B3 = asbf(b3w);
    f32x4 y[4];
#pragma unroll
    for (int n = 0; n < 4; ++n) {
      f32x4 yi = MFMA16(B1b[n], L2B1, bias2v[n], 0, 0, 0);
      yi = MFMA16(B2b[n], L2B1, yi, 0, 0, 0);
      yi = MFMA16(B1b[n], L2B3, yi, 0, 0, 0);
      y[n] = yi;
    }
    f32x4 h2v;
#pragma unroll
    for (int r = 0; r < 4; ++r) {
      float ig = sigmoidf_(y[0][r]);
      float fg = sigmoidf_(y[1][r]);
      float gg = fmaxf(y[2][r], 0.f);
      float og = sigmoidf_(y[3][r]);
      float cc = fg * c2[r] + ig * gg;
      c2[r] = cc;
      h2v[r] = og * fmaxf(cc, 0.f);
    }
    uint32_t p01h, p01l, p23h, p23l;
    pack_hl(h2v[0], h2v[1], p01h, p01l);
    pack_hl(h2v[2], h2v[3], p23h, p23l);
    h2ph[0] = bperm(addrA, p01h); h2ph[1] = bperm(addrA, p23h);
    h2ph[2] = bperm(addrB, p01h); h2ph[3] = bperm(addrB, p23h);
    h2pl[0] = bperm(addrA, p01l); h2pl[1] = bperm(addrA, p23l);
    h2pl[2] = bperm(addrB, p01l); h2pl[3] = bperm(addrB, p23l);
  }

  // ================= FC head (swapped layout) =================
  // B-frag: K = [h2hi(16) | h2lo(16)]
  u32x4 bwf;
#pragma unroll
  for (int q = 0; q < 4; ++q) bwf[q] = (g < 2) ? h2ph[q] : h2pl[q];
  bf16x8 Bfc = asbf(bwf);

  f32x4 acc2[2];
#pragma unroll
  for (int nn = 0; nn < 2; ++nn)
    acc2[nn] = *(const f32x4*)(bfc2 + 16 * nn + 4 * g);

  for (int kc = 0; kc < 16; ++kc) {
#pragma unroll
    for (int t = 0; t < 2; ++t) {
      const int mt = 2 * kc + t;
      bf16x8 A1h, A1l;
#pragma unroll
      for (int j = 0; j < 8; ++j) {
        float w = Wfc1[((8 * g + j) & 15) * 512 + 16 * mt + col];
        short h, l; split_hl(w, h, l);
        A1h[j] = h; A1l[j] = l;
      }
      f32x4 bv = *(const f32x4*)(bfc1 + 16 * mt + 4 * g);
      f32x4 acc = MFMA16(A1h, Bfc, bv, 0, 0, 0);
      acc = MFMA16(A1l, Bfc, acc, 0, 0, 0);
      uint32_t q01h, q01l, q23h, q23l;
      pack_hl(fmaxf(acc[0], 0.f), fmaxf(acc[1], 0.f), q01h, q01l);
      pack_hl(fmaxf(acc[2], 0.f), fmaxf(acc[3], 0.f), q23h, q23l);
      *(u32x2*)(cfh + col * 80 + 32 * t + 8 * g) = (u32x2){q01h, q23h};
      *(u32x2*)(cfl + col * 80 + 32 * t + 8 * g) = (u32x2){q01l, q23l};
    }
    lds_fence();
    bf16x8 Bh = *(const bf16x8*)(cfh + col * 80 + 16 * g);
    bf16x8 Bl = *(const bf16x8*)(cfl + col * 80 + 16 * g);
#pragma unroll
    for (int nn = 0; nn < 2; ++nn) {
      bf16x8 A2h, A2l;
#pragma unroll
      for (int j = 0; j < 8; ++j) {
        float w = Wfc2[(size_t)(32 * kc + 8 * g + j) * 32 + 16 * nn + col];
        short h, l; split_hl(w, h, l);
        A2h[j] = h; A2l[j] = l;
      }
      acc2[nn] = MFMA16(A2h, Bh, acc2[nn], 0, 0, 0);
      acc2[nn] = MFMA16(A2h, Bl, acc2[nn], 0, 0, 0);
      acc2[nn] = MFMA16(A2l, Bh, acc2[nn], 0, 0, 0);
    }
    lds_fence();   // WAR: next kc overwrites staging
  }

  // out[b][32]: lane(col,g) holds rows 16nn+4g+r of batch base+col
#pragma unroll
  for (int nn = 0; nn < 2; ++nn)
    *(f32x4*)(out + (size_t)(base + col) * 32 + 16 * nn + 4 * g) = acc2[nn];
}

extern "C" void kernel_launch(void* const* d_in, const int* in_sizes, int n_in,
                              void* d_out, int out_size, void* d_ws, size_t ws_size,
                              hipStream_t stream) {
  const float* x    = (const float*)d_in[0];
  const float* W1   = (const float*)d_in[1];
  const float* U1   = (const float*)d_in[2];
  const float* b1   = (const float*)d_in[3];
  const float* W2   = (const float*)d_in[4];
  const float* U2   = (const float*)d_in[5];
  const float* b2   = (const float*)d_in[6];
  const float* Wfc1 = (const float*)d_in[7];
  const float* bfc1 = (const float*)d_in[8];
  const float* Wfc2 = (const float*)d_in[9];
  const float* bfc2 = (const float*)d_in[10];

  lstm_fused<<<dim3(512), dim3(256), 0, stream>>>(
      x, W1, U1, b1, W2, U2, b2, Wfc1, bfc1, Wfc2, bfc2, (float*)d_out);
}